// Round 8
// baseline (482.020 us; speedup 1.0000x reference)
//
#include <hip/hip_runtime.h>
#include <hip/hip_bf16.h>

#define HIDDEN 1024
#define FFN    2816
#define NEXP   8
#define NTOK   2048

typedef __attribute__((ext_vector_type(8))) short short8;   // 8 bf16 = 4 VGPRs
typedef __attribute__((ext_vector_type(4))) short bf16x4;   // 4 bf16 = 8 B
typedef __attribute__((ext_vector_type(4))) float f32x4;

static __device__ __forceinline__ short f2bf(float f) {
    __hip_bfloat16 h = __float2bfloat16(f);
    return *(short*)&h;
}

// pack 8 fp32 -> 8 bf16 into one 16-B LDS slot
static __device__ __forceinline__ void pk8(short* dst, float4 A, float4 B) {
    short8 o;
    o[0] = f2bf(A.x); o[1] = f2bf(A.y); o[2] = f2bf(A.z); o[3] = f2bf(A.w);
    o[4] = f2bf(B.x); o[5] = f2bf(B.y); o[6] = f2bf(B.z); o[7] = f2bf(B.w);
    *(short8*)dst = o;
}

// async 16-B global->LDS DMA (lane i lands at ldsbase + i*16)
static __device__ __forceinline__ void gl_lds16(const short* g, short* l) {
    __builtin_amdgcn_global_load_lds(
        (const __attribute__((address_space(1))) void*)g,
        (__attribute__((address_space(3))) void*)l, 16, 0, 0);
}

#define WAITV(N) asm volatile("s_waitcnt vmcnt(" #N ")" ::: "memory")
#define LGKM0    asm volatile("s_waitcnt lgkmcnt(0)" ::: "memory")
#define BAR()    do { __builtin_amdgcn_s_barrier(); \
                      __builtin_amdgcn_sched_barrier(0); } while (0)

// ---------------- Router body (shared) -----------------------------------------
static __device__ __forceinline__ void
router_body(int t, int lane, const float* __restrict__ x,
            const float* __restrict__ Wgate, int* __restrict__ counts,
            int* __restrict__ tok, float* __restrict__ wts)
{
    float acc[NEXP];
#pragma unroll
    for (int e = 0; e < NEXP; e++) acc[e] = 0.f;
    const float* xrow = x + (size_t)t * HIDDEN;
    for (int h = lane; h < HIDDEN; h += 64) {
        float xv = xrow[h];
#pragma unroll
        for (int e = 0; e < NEXP; e++) acc[e] += xv * Wgate[e * HIDDEN + h];
    }
#pragma unroll
    for (int off = 32; off > 0; off >>= 1) {
#pragma unroll
        for (int e = 0; e < NEXP; e++) acc[e] += __shfl_down(acc[e], off);
    }
    if (lane == 0) {
        float mx = acc[0];
#pragma unroll
        for (int e = 1; e < NEXP; e++) mx = fmaxf(mx, acc[e]);
        float p[NEXP];
#pragma unroll
        for (int e = 0; e < NEXP; e++) p[e] = __expf(acc[e] - mx);
        int i0 = 0; float p0 = p[0];
#pragma unroll
        for (int e = 1; e < NEXP; e++) if (p[e] > p0) { p0 = p[e]; i0 = e; }
        int i1 = -1; float p1 = -1.f;
#pragma unroll
        for (int e = 0; e < NEXP; e++) {
            if (e == i0) continue;
            if (p[e] > p1) { p1 = p[e]; i1 = e; }
        }
        float inv = 1.f / (p0 + p1);
        float w0 = p0 * inv, w1 = p1 * inv;
        int s0 = atomicAdd(&counts[i0], 1);
        tok[i0 * NTOK + s0] = t; wts[i0 * NTOK + s0] = w0;
        int s1 = atomicAdd(&counts[i1], 1);
        tok[i1 * NTOK + s1] = t; wts[i1 * NTOK + s1] = w1;
    }
}

__global__ void __launch_bounds__(64)
router_kernel(const float* __restrict__ x, const float* __restrict__ Wgate,
              int* __restrict__ counts, int* __restrict__ tok,
              float* __restrict__ wts)
{
    router_body(blockIdx.x, threadIdx.x, x, Wgate, counts, tok, wts);
}

// fast-path router: 512 blocks x 4 waves = 2048 tokens
__global__ void __launch_bounds__(256)
router4(const float* __restrict__ x, const float* __restrict__ Wgate,
        int* __restrict__ counts, int* __restrict__ tok,
        float* __restrict__ wts)
{
    router_body(blockIdx.x * 4 + (threadIdx.x >> 6), threadIdx.x & 63,
                x, Wgate, counts, tok, wts);
}

// ---------------- Stage A: 8-wave 128x128 tile, all-fp32-direct ----------------
// 512 threads = 8 waves; wave w owns a 64x32 output sub-tile (wm=(w&1)*64,
// wn=(w>>1)*32) and stages rows [w*16, w*16+16) of X/G/U per K-step.
// rbase = w*16 is a multiple of 16, so the verified swizzle invariant
// (slot s of row r holds chunk s^((r>>1)&3); gchunk=(l&3)^((l>>3)&3)) holds:
// for lane 4p+c, (lane>>3)&3 == (p>>1)&3 == ((rbase+p)>>1)&3 since 8w===0 mod 4.
// x read fp32 + converted in-kernel -> xbf pre-pass eliminated entirely.
// Tail blocks [2816, 3072): zero out (completes before ffn2 launch by stream
// ordering).  Per wave per K-step: 6 float4 loads, 16 MFMA.
#define FFN1_BLOCKS 2816
#define ZERO_BLOCKS 256
__global__ void __launch_bounds__(512, 2)
ffn1_v11(const float* __restrict__ x, const float* __restrict__ Wg,
         const float* __restrict__ Wu, const int* __restrict__ counts,
         const int* __restrict__ tok, short* __restrict__ hbuf,
         float* __restrict__ out)
{
    int bid = blockIdx.x;
    int tid = threadIdx.x;
    if (bid >= FFN1_BLOCKS) {
        // zero out: 256 blocks x (512 thr x 4) float4 = 524288 f4 = 8 MB
        long long b4 = (long long)(bid - FFN1_BLOCKS) * 2048 + tid;
        float4 z = make_float4(0.f, 0.f, 0.f, 0.f);
#pragma unroll
        for (int p = 0; p < 4; p++) ((float4*)out)[b4 + p * 512] = z;
        return;
    }
    int xb  = bid / 176;          // SLOWEST (round-3 verified XCD ordering)
    int yz  = bid - xb * 176;
    int e   = yz / 22;
    int fb  = yz - e * 22;
    int cnt = counts[e];
    int row0 = xb * 128;
    if (row0 >= cnt) return;
    int off_e = 0;
#pragma unroll
    for (int i = 0; i < NEXP; i++) if (i < e) off_e += counts[i];
    int f0 = fb * 128;

    __shared__ short Xs[2][128 * 32];
    __shared__ short Gs[2][128 * 32];
    __shared__ short Us[2][128 * 32];

    int lane = tid & 63, w = tid >> 6;          // w = 0..7
    int l15 = lane & 15, lq = lane >> 4;
    int wm = (w & 1) * 64, wn = (w >> 1) * 32;

    int prow   = lane >> 2;                     // 0..15
    int gchunk = (lane & 3) ^ ((lane >> 3) & 3);
    int rbase  = w * 16;
    int srow   = min(row0 + rbase + prow, cnt - 1);
    int tkn    = tok[e * NTOK + srow];
    const float* xsrc = x  + (size_t)tkn * HIDDEN + gchunk * 8;
    const float* gsrc = Wg + (size_t)e * FFN * HIDDEN
                           + (size_t)(f0 + rbase + prow) * HIDDEN + gchunk * 8;
    const float* usrc = Wu + (size_t)e * FFN * HIDDEN
                           + (size_t)(f0 + rbase + prow) * HIDDEN + gchunk * 8;
    int wadr = rbase * 32 + lane * 8;           // shorts: 16-B slot per lane

    int aoff[4], boff[2];
#pragma unroll
    for (int mi = 0; mi < 4; mi++) {
        int r = wm + mi * 16 + l15;
        aoff[mi] = r * 32 + (lq ^ ((r >> 1) & 3)) * 8;
    }
#pragma unroll
    for (int ni = 0; ni < 2; ni++) {
        int r = wn + ni * 16 + l15;
        boff[ni] = r * 32 + (lq ^ ((r >> 1) & 3)) * 8;
    }

    f32x4 cg[4][2], cu[4][2];
#pragma unroll
    for (int i = 0; i < 4; i++)
#pragma unroll
        for (int j = 0; j < 2; j++) { cg[i][j] = (f32x4)0.f; cu[i][j] = (f32x4)0.f; }

    float4 xa_, xb_, ga_, gb_, ua_, ub_;        // single staging set (24 VGPR)

#define LOAD1(T) do { int _k = (T) * 32;                            \
    xa_ = *(const float4*)(xsrc + _k); xb_ = *(const float4*)(xsrc + _k + 4); \
    ga_ = *(const float4*)(gsrc + _k); gb_ = *(const float4*)(gsrc + _k + 4); \
    ua_ = *(const float4*)(usrc + _k); ub_ = *(const float4*)(usrc + _k + 4); } while (0)

#define CVT1(B) do {                                                \
    pk8(&Xs[B][wadr], xa_, xb_);                                    \
    pk8(&Gs[B][wadr], ga_, gb_);                                    \
    pk8(&Us[B][wadr], ua_, ub_); } while (0)

#define COMP1(B) do {                                               \
    short8 af[4], bg[2], bu[2];                                     \
    _Pragma("unroll")                                               \
    for (int mi = 0; mi < 4; mi++)                                  \
        af[mi] = *(const short8*)&Xs[B][aoff[mi]];                  \
    _Pragma("unroll")                                               \
    for (int ni = 0; ni < 2; ni++) {                                \
        bg[ni] = *(const short8*)&Gs[B][boff[ni]];                  \
        bu[ni] = *(const short8*)&Us[B][boff[ni]];                  \
    }                                                               \
    _Pragma("unroll")                                               \
    for (int mi = 0; mi < 4; mi++)                                  \
    _Pragma("unroll")                                               \
    for (int ni = 0; ni < 2; ni++) {                                \
        cg[mi][ni] = __builtin_amdgcn_mfma_f32_16x16x32_bf16(af[mi], bg[ni], cg[mi][ni], 0, 0, 0); \
        cu[mi][ni] = __builtin_amdgcn_mfma_f32_16x16x32_bf16(af[mi], bu[ni], cu[mi][ni], 0, 0, 0); \
    } } while (0)

    LOAD1(0);
    for (int tt = 0; tt < 32; tt += 2) {
        CVT1(0);                 // compiler auto-waits tile tt's loads
        LOAD1(tt + 1);
        LGKM0; BAR();
        COMP1(0);
        BAR();
        CVT1(1);
        if (tt + 2 < 32) LOAD1(tt + 2);
        LGKM0; BAR();
        COMP1(1);
        BAR();
    }

#undef LOAD1
#undef CVT1
#undef COMP1

    // epilogue: silu(g)*u -> bf16 hbuf.  C/D: col=lane&15, row=lq*4+reg
#pragma unroll
    for (int mi = 0; mi < 4; mi++)
#pragma unroll
        for (int r = 0; r < 4; r++) {
            int row = wm + mi * 16 + lq * 4 + r;
            int grow = row0 + row;
            if (grow < cnt) {
                short* hrow = hbuf + (size_t)(off_e + grow) * FFN + f0 + wn;
#pragma unroll
                for (int ni = 0; ni < 2; ni++) {
                    float g = cg[mi][ni][r], u = cu[mi][ni][r];
                    float h = g / (1.f + __expf(-g)) * u;
                    hrow[ni * 16 + l15] = f2bf(h);
                }
            }
        }
}

// ---------------- Stage B: 8-wave 128x128 tile, fp32 Wd direct -----------------
// Same 8-wave decomposition.  H (bf16) via 1 DMA/wave/K-step; Wd (fp32) via
// 2 reg loads + convert.  The pk8 reg-dependency forces a conservative vmcnt
// drain before each barrier; explicit WAITV is belt-and-braces for the H-DMA.
__global__ void __launch_bounds__(512, 2)
ffn2_v11(const short* __restrict__ hbuf, const float* __restrict__ Wd,
         const int* __restrict__ counts, const int* __restrict__ tok,
         const float* __restrict__ wts, float* __restrict__ out)
{
    int bid = blockIdx.x;
    int xb  = bid >> 7;           // SLOWEST
    int yz  = bid & 127;
    int e   = yz >> 4;
    int y   = yz & 15;
    int cnt = counts[e];
    int row0 = xb * 128;
    if (row0 >= cnt) return;
    int off_e = 0;
#pragma unroll
    for (int i = 0; i < NEXP; i++) if (i < e) off_e += counts[i];
    int h0    = (y >> 1) * 128;
    int kbase = (y & 1) * (FFN / 2);

    __shared__ short Hs[2][128 * 32];
    __shared__ short Ds[2][128 * 32];
    __shared__ int   stok[128];
    __shared__ float swt[128];

    int tid = threadIdx.x;
    if (tid < 128) {
        int rc = min(row0 + tid, cnt - 1);
        stok[tid] = tok[e * NTOK + rc];
        swt[tid]  = wts[e * NTOK + rc];
    }
    __syncthreads();

    int lane = tid & 63, w = tid >> 6;
    int l15 = lane & 15, lq = lane >> 4;
    int wm = (w & 1) * 64, wn = (w >> 1) * 32;

    int prow   = lane >> 2;
    int gchunk = (lane & 3) ^ ((lane >> 3) & 3);
    int rbase  = w * 16;
    const short* hsrc = hbuf + (size_t)(off_e + min(row0 + rbase + prow, cnt - 1)) * FFN
                             + kbase + gchunk * 8;
    const float* dsrc = Wd + (size_t)e * HIDDEN * FFN
                           + (size_t)(h0 + rbase + prow) * FFN + kbase + gchunk * 8;
    int wadr = rbase * 32 + lane * 8;

    int aoff[4], boff[2];
#pragma unroll
    for (int mi = 0; mi < 4; mi++) {
        int r = wm + mi * 16 + l15;
        aoff[mi] = r * 32 + (lq ^ ((r >> 1) & 3)) * 8;
    }
#pragma unroll
    for (int ni = 0; ni < 2; ni++) {
        int r = wn + ni * 16 + l15;
        boff[ni] = r * 32 + (lq ^ ((r >> 1) & 3)) * 8;
    }

    f32x4 c[4][2];
#pragma unroll
    for (int i = 0; i < 4; i++)
#pragma unroll
        for (int j = 0; j < 2; j++) c[i][j] = (f32x4)0.f;

    float4 da_, db_;

#define HDMA(B, T) gl_lds16(hsrc + (T) * 32, &Hs[B][rbase * 32])

#define LOADD(T) do { int _k = (T) * 32;                            \
    da_ = *(const float4*)(dsrc + _k);                              \
    db_ = *(const float4*)(dsrc + _k + 4); } while (0)

#define COMP2(B) do {                                               \
    short8 af[4], bd[2];                                            \
    _Pragma("unroll")                                               \
    for (int mi = 0; mi < 4; mi++)                                  \
        af[mi] = *(const short8*)&Hs[B][aoff[mi]];                  \
    _Pragma("unroll")                                               \
    for (int ni = 0; ni < 2; ni++)                                  \
        bd[ni] = *(const short8*)&Ds[B][boff[ni]];                  \
    _Pragma("unroll")                                               \
    for (int mi = 0; mi < 4; mi++)                                  \
    _Pragma("unroll")                                               \
    for (int ni = 0; ni < 2; ni++)                                  \
        c[mi][ni] = __builtin_amdgcn_mfma_f32_16x16x32_bf16(af[mi], bd[ni], c[mi][ni], 0, 0, 0); \
    } while (0)

    // NT = (FFN/2)/32 = 44 tiles
    HDMA(0, 0); LOADD(0);

    for (int tt = 0; tt < 44; tt += 2) {
        pk8(&Ds[0][wadr], da_, db_);          // auto-waits tile tt's Wd loads
        HDMA(1, tt + 1); LOADD(tt + 1);
        WAITV(3); LGKM0; BAR();               // HDMA(tt) drained before use
        COMP2(0);
        BAR();
        pk8(&Ds[1][wadr], da_, db_);
        if (tt + 2 < 44) { HDMA(0, tt + 2); LOADD(tt + 2); WAITV(3); }
        else             { WAITV(0); }
        LGKM0; BAR();
        COMP2(1);
        BAR();
    }

#undef HDMA
#undef LOADD
#undef COMP2

#pragma unroll
    for (int mi = 0; mi < 4; mi++)
#pragma unroll
        for (int r = 0; r < 4; r++) {
            int row = wm + mi * 16 + lq * 4 + r;
            int grow = row0 + row;
            if (grow < cnt) {
                int t = stok[row];
                float wgt = swt[row];
                float* orow = out + (size_t)t * HIDDEN + h0 + wn;
#pragma unroll
                for (int ni = 0; ni < 2; ni++)
                    atomicAdd(&orow[ni * 16 + l15], wgt * c[mi][ni][r]);
            }
        }
}

// ================= Fallback path (R2 kernels, used if ws too small) ============
#define LDW 40
__global__ void __launch_bounds__(256, 2)
ffn1_fb(const float* __restrict__ x, const float* __restrict__ Wg,
        const float* __restrict__ Wu, const int* __restrict__ counts,
        const int* __restrict__ tok, __hip_bfloat16* __restrict__ hbuf)
{
    int e = blockIdx.z;
    int cnt = counts[e];
    int row0 = blockIdx.x * 128;
    if (row0 >= cnt) return;
    int off_e = 0;
#pragma unroll
    for (int i = 0; i < NEXP; i++) if (i < e) off_e += counts[i];
    int f0 = blockIdx.y * 64;

    __shared__ short Xs[128][LDW];
    __shared__ short Gs[64][LDW];
    __shared__ short Us[64][LDW];
    __shared__ int   stok[128];

    int tid = threadIdx.x;
    if (tid < 128) stok[tid] = tok[e * NTOK + min(row0 + tid, cnt - 1)];
    __syncthreads();

    int lane = tid & 63, w = tid >> 6;
    int wm = (w & 1) * 64, wn = (w >> 1) * 32;
    int l15 = lane & 15, lq = lane >> 4;

    f32x4 cg[4][2], cu[4][2];
#pragma unroll
    for (int i = 0; i < 4; i++)
#pragma unroll
        for (int j = 0; j < 2; j++) { cg[i][j] = (f32x4)0.f; cu[i][j] = (f32x4)0.f; }

    const float* Wge = Wg + (size_t)e * FFN * HIDDEN;
    const float* Wue = Wu + (size_t)e * FFN * HIDDEN;

    int xr[4], xc[4]; const float* xp[4];
#pragma unroll
    for (int i = 0; i < 4; i++) {
        int idx = tid + 256 * i;
        xr[i] = idx >> 3; xc[i] = (idx & 7) * 4;
        xp[i] = x + (size_t)stok[xr[i]] * HIDDEN + xc[i];
    }
    int wr[2], wc[2]; const float* gp[2]; const float* up[2];
#pragma unroll
    for (int i = 0; i < 2; i++) {
        int idx = tid + 256 * i;
        wr[i] = idx >> 3; wc[i] = (idx & 7) * 4;
        gp[i] = Wge + (size_t)(f0 + wr[i]) * HIDDEN + wc[i];
        up[i] = Wue + (size_t)(f0 + wr[i]) * HIDDEN + wc[i];
    }

    float4 xa[4], ga[2], ua[2];
#pragma unroll
    for (int i = 0; i < 4; i++) xa[i] = *(const float4*)(xp[i]);
#pragma unroll
    for (int i = 0; i < 2; i++) { ga[i] = *(const float4*)(gp[i]); ua[i] = *(const float4*)(up[i]); }

    for (int k0 = 0; k0 < HIDDEN; k0 += 32) {
        __syncthreads();
#pragma unroll
        for (int i = 0; i < 4; i++) {
            short* d = &Xs[xr[i]][xc[i]];
            d[0] = f2bf(xa[i].x); d[1] = f2bf(xa[i].y);
            d[2] = f2bf(xa[i].z); d[3] = f2bf(xa[i].w);
        }
#pragma unroll
        for (int i = 0; i < 2; i++) {
            short* d = &Gs[wr[i]][wc[i]];
            d[0] = f2bf(ga[i].x); d[1] = f2bf(ga[i].y);
            d[2] = f2bf(ga[i].z); d[3] = f2bf(ga[i].w);
            short* d2 = &Us[wr[i]][wc[i]];
            d2[0] = f2bf(ua[i].x); d2[1] = f2bf(ua[i].y);
            d2[2] = f2bf(ua[i].z); d2[3] = f2bf(ua[i].w);
        }
        __syncthreads();
        if (k0 + 32 < HIDDEN) {
            int kn = k0 + 32;
#pragma unroll
            for (int i = 0; i < 4; i++) xa[i] = *(const float4*)(xp[i] + kn);
#pragma unroll
            for (int i = 0; i < 2; i++) { ga[i] = *(const float4*)(gp[i] + kn); ua[i] = *(const float4*)(up[i] + kn); }
        }
        short8 af[4], bg[2], bu[2];
#pragma unroll
        for (int mi = 0; mi < 4; mi++) af[mi] = *(const short8*)&Xs[wm + mi * 16 + l15][lq * 8];
#pragma unroll
        for (int ni = 0; ni < 2; ni++) {
            bg[ni] = *(const short8*)&Gs[wn + ni * 16 + l15][lq * 8];
            bu[ni] = *(const short8*)&Us[wn + ni * 16 + l15][lq * 8];
        }
#pragma unroll
        for (int mi = 0; mi < 4; mi++)
#pragma unroll
            for (int ni = 0; ni < 2; ni++) {
                cg[mi][ni] = __builtin_amdgcn_mfma_f32_16x16x32_bf16(af[mi], bg[ni], cg[mi][ni], 0, 0, 0);
                cu[mi][ni] = __builtin_amdgcn_mfma_f32_16x16x32_bf16(af[mi], bu[ni], cu[mi][ni], 0, 0, 0);
            }
    }

#pragma unroll
    for (int mi = 0; mi < 4; mi++)
#pragma unroll
        for (int r = 0; r < 4; r++) {
            int row = wm + mi * 16 + lq * 4 + r;
            int grow = row0 + row;
            if (grow < cnt) {
                __hip_bfloat16* hrow = hbuf + (size_t)(off_e + grow) * FFN + f0 + wn;
#pragma unroll
                for (int ni = 0; ni < 2; ni++) {
                    float g = cg[mi][ni][r], u = cu[mi][ni][r];
                    float h = g / (1.f + __expf(-g)) * u;
                    hrow[ni * 16 + l15] = __float2bfloat16(h);
                }
            }
        }
}

__global__ void __launch_bounds__(256, 2)
ffn2_fb(const __hip_bfloat16* __restrict__ hbuf, const float* __restrict__ Wd,
        const int* __restrict__ counts, const int* __restrict__ tok,
        const float* __restrict__ wts, float* __restrict__ out)
{
    int e = blockIdx.z;
    int cnt = counts[e];
    int row0 = blockIdx.x * 128;
    if (row0 >= cnt) return;
    int off_e = 0;
#pragma unroll
    for (int i = 0; i < NEXP; i++) if (i < e) off_e += counts[i];
    int h0 = blockIdx.y * 64;

    __shared__ short Hs[128][LDW];
    __shared__ short Ds[64][LDW];
    __shared__ int   stok[128];
    __shared__ float swt[128];

    int tid = threadIdx.x;
    if (tid < 128) {
        int rc = min(row0 + tid, cnt - 1);
        stok[tid] = tok[e * NTOK + rc];
        swt[tid]  = wts[e * NTOK + rc];
    }
    __syncthreads();

    int lane = tid & 63, w = tid >> 6;
    int wm = (w & 1) * 64, wn = (w >> 1) * 32;
    int l15 = lane & 15, lq = lane >> 4;

    f32x4 c[4][2];
#pragma unroll
    for (int i = 0; i < 4; i++)
#pragma unroll
        for (int j = 0; j < 2; j++) c[i][j] = (f32x4)0.f;

    const float* Wde = Wd + (size_t)e * HIDDEN * FFN;

    int hr[2], hc[2]; const short* hp[2];
#pragma unroll
    for (int i = 0; i < 2; i++) {
        int idx = tid + 256 * i;
        hr[i] = idx >> 2; hc[i] = (idx & 3) * 8;
        int ar = min(row0 + hr[i], cnt - 1);
        hp[i] = (const short*)(hbuf + (size_t)(off_e + ar) * FFN + hc[i]);
    }
    int dr[2], dc[2]; const float* dp[2];
#pragma unroll
    for (int i = 0; i < 2; i++) {
        int idx = tid + 256 * i;
        dr[i] = idx >> 3; dc[i] = (idx & 7) * 4;
        dp[i] = Wde + (size_t)(h0 + dr[i]) * FFN + dc[i];
    }

    short8 ha[2]; float4 da[2];
#pragma unroll
    for (int i = 0; i < 2; i++) { ha[i] = *(const short8*)(hp[i]); da[i] = *(const float4*)(dp[i]); }

    for (int k0 = 0; k0 < FFN; k0 += 32) {
        __syncthreads();
#pragma unroll
        for (int i = 0; i < 2; i++) {
            *(short8*)&Hs[hr[i]][hc[i]] = ha[i];
            short* d = &Ds[dr[i]][dc[i]];
            d[0] = f2bf(da[i].x); d[1] = f2bf(da[i].y);
            d[2] = f2bf(da[i].z); d[3] = f2bf(da[i].w);
        }
        __syncthreads();
        if (k0 + 32 < FFN) {
            int kn = k0 + 32;
#pragma unroll
            for (int i = 0; i < 2; i++) { ha[i] = *(const short8*)(hp[i] + kn); da[i] = *(const float4*)(dp[i] + kn); }
        }
        short8 af[4], bf_[2];
#pragma unroll
        for (int mi = 0; mi < 4; mi++) af[mi] = *(const short8*)&Hs[wm + mi * 16 + l15][lq * 8];
#pragma unroll
        for (int ni = 0; ni < 2; ni++) bf_[ni] = *(const short8*)&Ds[wn + ni * 16 + l15][lq * 8];
#pragma unroll
        for (int mi = 0; mi < 4; mi++)
#pragma unroll
            for (int ni = 0; ni < 2; ni++)
                c[mi][ni] = __builtin_amdgcn_mfma_f32_16x16x32_bf16(af[mi], bf_[ni], c[mi][ni], 0, 0, 0);
    }

#pragma unroll
    for (int mi = 0; mi < 4; mi++)
#pragma unroll
        for (int r = 0; r < 4; r++) {
            int row = wm + mi * 16 + lq * 4 + r;
            int grow = row0 + row;
            if (grow < cnt) {
                int t = stok[row];
                float wgt = swt[row];
                float* orow = out + (size_t)t * HIDDEN + h0 + wn;
#pragma unroll
                for (int ni = 0; ni < 2; ni++)
                    atomicAdd(&orow[ni * 16 + l15], wgt * c[mi][ni][r]);
            }
        }
}

extern "C" void kernel_launch(void* const* d_in, const int* in_sizes, int n_in,
                              void* d_out, int out_size, void* d_ws, size_t ws_size,
                              hipStream_t stream) {
    const float* x     = (const float*)d_in[0];
    const float* Wgate = (const float*)d_in[1];
    const float* Wg    = (const float*)d_in[2];
    const float* Wu    = (const float*)d_in[3];
    const float* Wd    = (const float*)d_in[4];
    float* out = (float*)d_out;

    char* ws = (char*)d_ws;
    int*   counts = (int*)ws;
    int*   tok    = (int*)(ws + 256);
    float* wts    = (float*)(ws + 256 + NEXP * NTOK * 4);

    hipMemsetAsync(counts, 0, 256, stream);

    const size_t base = 256 + 2 * (size_t)NEXP * NTOK * 4;   // 131328
    const size_t NEED = base + 2ull * 2ull * NTOK * FFN;     // hbuf only

    if (ws_size >= NEED) {
        short* hbuf = (short*)(ws + base);

        // launch 1: router (512 blocks x 4 waves)
        router4<<<512, 256, 0, stream>>>(x, Wgate, counts, tok, wts);

        // launch 2: ffn1 (8-wave, all-fp32-direct) + out-zero tail blocks
        ffn1_v11<<<FFN1_BLOCKS + ZERO_BLOCKS, 512, 0, stream>>>(
            x, Wg, Wu, counts, tok, hbuf, out);

        // launch 3: ffn2 (8-wave, fp32 Wd direct)
        ffn2_v11<<<2048, 512, 0, stream>>>(hbuf, Wd, counts, tok, wts, out);
    } else {
        hipMemsetAsync(out, 0, (size_t)out_size * sizeof(float), stream);
        router_kernel<<<NTOK, 64, 0, stream>>>(x, Wgate, counts, tok, wts);
        __hip_bfloat16* hbuf = (__hip_bfloat16*)(ws + base);
        dim3 g1(NTOK / 128, FFN / 64, NEXP);
        ffn1_fb<<<g1, 256, 0, stream>>>(x, Wg, Wu, counts, tok, hbuf);
        dim3 g2(NTOK / 128, HIDDEN / 64, NEXP);
        ffn2_fb<<<g2, 256, 0, stream>>>(hbuf, Wd, counts, tok, wts, out);
    }
}

// Round 9
// 448.612 us; speedup vs baseline: 1.0745x; 1.0745x over previous
//
#include <hip/hip_runtime.h>
#include <hip/hip_bf16.h>

#define HIDDEN 1024
#define FFN    2816
#define NEXP   8
#define NTOK   2048

typedef __attribute__((ext_vector_type(8))) short short8;   // 8 bf16 = 4 VGPRs
typedef __attribute__((ext_vector_type(4))) short bf16x4;   // 4 bf16 = 8 B
typedef __attribute__((ext_vector_type(4))) float f32x4;

static __device__ __forceinline__ short f2bf(float f) {
    __hip_bfloat16 h = __float2bfloat16(f);
    return *(short*)&h;
}

// pack 8 fp32 -> 8 bf16 into one 16-B LDS slot
static __device__ __forceinline__ void pk8(short* dst, float4 A, float4 B) {
    short8 o;
    o[0] = f2bf(A.x); o[1] = f2bf(A.y); o[2] = f2bf(A.z); o[3] = f2bf(A.w);
    o[4] = f2bf(B.x); o[5] = f2bf(B.y); o[6] = f2bf(B.z); o[7] = f2bf(B.w);
    *(short8*)dst = o;
}

// async 16-B global->LDS DMA (lane i lands at ldsbase + i*16)
static __device__ __forceinline__ void gl_lds16(const short* g, short* l) {
    __builtin_amdgcn_global_load_lds(
        (const __attribute__((address_space(1))) void*)g,
        (__attribute__((address_space(3))) void*)l, 16, 0, 0);
}

#define WAITV(N) asm volatile("s_waitcnt vmcnt(" #N ")" ::: "memory")
#define LGKM0    asm volatile("s_waitcnt lgkmcnt(0)" ::: "memory")
#define BAR()    do { __builtin_amdgcn_s_barrier(); \
                      __builtin_amdgcn_sched_barrier(0); } while (0)

// ---------------- Router body (shared) -----------------------------------------
static __device__ __forceinline__ void
router_body(int t, int lane, const float* __restrict__ x,
            const float* __restrict__ Wgate, int* __restrict__ counts,
            int* __restrict__ tok, float* __restrict__ wts)
{
    float acc[NEXP];
#pragma unroll
    for (int e = 0; e < NEXP; e++) acc[e] = 0.f;
    const float* xrow = x + (size_t)t * HIDDEN;
    for (int h = lane; h < HIDDEN; h += 64) {
        float xv = xrow[h];
#pragma unroll
        for (int e = 0; e < NEXP; e++) acc[e] += xv * Wgate[e * HIDDEN + h];
    }
#pragma unroll
    for (int off = 32; off > 0; off >>= 1) {
#pragma unroll
        for (int e = 0; e < NEXP; e++) acc[e] += __shfl_down(acc[e], off);
    }
    if (lane == 0) {
        float mx = acc[0];
#pragma unroll
        for (int e = 1; e < NEXP; e++) mx = fmaxf(mx, acc[e]);
        float p[NEXP];
#pragma unroll
        for (int e = 0; e < NEXP; e++) p[e] = __expf(acc[e] - mx);
        int i0 = 0; float p0 = p[0];
#pragma unroll
        for (int e = 1; e < NEXP; e++) if (p[e] > p0) { p0 = p[e]; i0 = e; }
        int i1 = -1; float p1 = -1.f;
#pragma unroll
        for (int e = 0; e < NEXP; e++) {
            if (e == i0) continue;
            if (p[e] > p1) { p1 = p[e]; i1 = e; }
        }
        float inv = 1.f / (p0 + p1);
        float w0 = p0 * inv, w1 = p1 * inv;
        int s0 = atomicAdd(&counts[i0], 1);
        tok[i0 * NTOK + s0] = t; wts[i0 * NTOK + s0] = w0;
        int s1 = atomicAdd(&counts[i1], 1);
        tok[i1 * NTOK + s1] = t; wts[i1 * NTOK + s1] = w1;
    }
}

__global__ void __launch_bounds__(64)
router_kernel(const float* __restrict__ x, const float* __restrict__ Wgate,
              int* __restrict__ counts, int* __restrict__ tok,
              float* __restrict__ wts)
{
    router_body(blockIdx.x, threadIdx.x, x, Wgate, counts, tok, wts);
}

// ---------------- Launch 1: router + x->bf16 + out-zero (round-6 proven) -------
__global__ void __launch_bounds__(256)
fused_rxz(const float* __restrict__ x, const float* __restrict__ Wgate,
          int* __restrict__ counts, int* __restrict__ tok,
          float* __restrict__ wts, short* __restrict__ xbf,
          float* __restrict__ out)
{
    int bid = blockIdx.x;
    int tid = threadIdx.x;
    if (bid < 512) {
        router_body(bid * 4 + (tid >> 6), tid & 63, x, Wgate, counts, tok, wts);
        return;
    }
    if (bid < 1024) {
        long long base4 = (long long)(bid - 512) * 1024;
#pragma unroll
        for (int p = 0; p < 4; p++) {
            long long r = base4 + p * 256 + tid;
            float4 a = ((const float4*)x)[r];
            bf16x4 o;
            o[0] = f2bf(a.x); o[1] = f2bf(a.y); o[2] = f2bf(a.z); o[3] = f2bf(a.w);
            *(bf16x4*)(xbf + 4 * r) = o;
        }
        return;
    }
    long long base4 = (long long)(bid - 1024) * 1024;
    float4 z = make_float4(0.f, 0.f, 0.f, 0.f);
#pragma unroll
    for (int p = 0; p < 4; p++)
        ((float4*)out)[base4 + p * 256 + tid] = z;
}

// ---------------- Stage A: BM=256 x BN=128 tile, 8 waves, demand-halved --------
// Demand model (round-8): GEMM time == demand-bytes / ~7 TB/s.  BM=256 halves
// the weight-replica demand (xb replicas 4 -> 2): 940 -> ~480 MB.
// 512 thr = 8 waves; wave w: wm=(w&3)*64 (4 row-groups), wn=(w>>2)*64 (2 col),
// 4x4 frags x {G,U} = 32 MFMA per wave per K-step (v10's compute-phase size).
// Staging per wave per K-step: X rows [w*32,w*32+32) via 2 DMA (bf16 xbf);
// G/U rows [w*16,w*16+16) via 2 fp32 float4-loads each + pk8 convert.
// All rbase values are multiples of 16 -> verified swizzle invariant holds
// (slot c of row r holds chunk c^((r>>1)&3); gchunk=(l&3)^((l>>3)&3)).
// vmcnt trace: 6 VMEM/wave/step; WAITV(6) drains exactly the consumed tile's
// X-DMA before each barrier (reg-deps drain the fp32 loads).  LDS 65 KB,
// VGPR ~180 -> 1 block/CU (8 waves, 2/SIMD) -- same waves/CU as v10.
#define FFN1_BLOCKS 1408     // 8 xb x (8 e x 22 fb), xb slowest
__global__ void __launch_bounds__(512, 2)
ffn1_v12(const short* __restrict__ xbf, const float* __restrict__ Wg,
         const float* __restrict__ Wu, const int* __restrict__ counts,
         const int* __restrict__ tok, short* __restrict__ hbuf)
{
    int bid = blockIdx.x;
    int tid = threadIdx.x;
    int xb  = bid / 176;
    int yz  = bid - xb * 176;
    int e   = yz / 22;
    int fb  = yz - e * 22;
    int cnt = counts[e];
    int row0 = xb * 256;
    if (row0 >= cnt) return;
    int off_e = 0;
#pragma unroll
    for (int i = 0; i < NEXP; i++) if (i < e) off_e += counts[i];
    int f0 = fb * 128;

    __shared__ short Xs[2][256 * 32];
    __shared__ short Gs[2][128 * 32];
    __shared__ short Us[2][128 * 32];
    __shared__ int   stok[256];

    if (tid < 256) stok[tid] = tok[e * NTOK + min(row0 + tid, cnt - 1)];
    __syncthreads();

    int lane = tid & 63, w = tid >> 6;          // w = 0..7
    int l15 = lane & 15, lq = lane >> 4;
    int wm = (w & 3) * 64, wn = (w >> 2) * 64;

    int prow   = lane >> 2;                     // 0..15
    int gchunk = (lane & 3) ^ ((lane >> 3) & 3);

    // X staging: two 16-row groups [w*32, w*32+32)
    const short* xsrc[2]; int xrb[2];
#pragma unroll
    for (int j = 0; j < 2; j++) {
        int rbase = w * 32 + j * 16;
        xsrc[j] = xbf + (size_t)stok[rbase + prow] * HIDDEN + gchunk * 8;
        xrb[j] = rbase * 32;
    }
    // G/U staging: one 16-row group [w*16, w*16+16)
    const float* gsrc = Wg + (size_t)e * FFN * HIDDEN
                           + (size_t)(f0 + w * 16 + prow) * HIDDEN + gchunk * 8;
    const float* usrc = Wu + (size_t)e * FFN * HIDDEN
                           + (size_t)(f0 + w * 16 + prow) * HIDDEN + gchunk * 8;
    int wadr = (w * 16) * 32 + lane * 8;        // pk8 slot == DMA-landing layout

    int aoff[4], boff[4];
#pragma unroll
    for (int mi = 0; mi < 4; mi++) {
        int r = wm + mi * 16 + l15;             // < 256
        aoff[mi] = r * 32 + (lq ^ ((r >> 1) & 3)) * 8;
    }
#pragma unroll
    for (int ni = 0; ni < 4; ni++) {
        int r = wn + ni * 16 + l15;             // < 128
        boff[ni] = r * 32 + (lq ^ ((r >> 1) & 3)) * 8;
    }

    f32x4 cg[4][4], cu[4][4];
#pragma unroll
    for (int i = 0; i < 4; i++)
#pragma unroll
        for (int j = 0; j < 4; j++) { cg[i][j] = (f32x4)0.f; cu[i][j] = (f32x4)0.f; }

    float4 ga_, gb_, ua_, ub_;                  // single staging set (16 VGPR)

#define XDMA(B, T) do { int _k = (T) * 32;                          \
    gl_lds16(xsrc[0] + _k, &Xs[B][xrb[0]]);                         \
    gl_lds16(xsrc[1] + _k, &Xs[B][xrb[1]]); } while (0)

#define LOADR(T) do { int _k = (T) * 32;                            \
    ga_ = *(const float4*)(gsrc + _k); gb_ = *(const float4*)(gsrc + _k + 4); \
    ua_ = *(const float4*)(usrc + _k); ub_ = *(const float4*)(usrc + _k + 4); } while (0)

#define CVTW(B) do {                                                \
    pk8(&Gs[B][wadr], ga_, gb_);                                    \
    pk8(&Us[B][wadr], ua_, ub_); } while (0)

#define COMP1(B) do {                                               \
    short8 af[4];                                                   \
    _Pragma("unroll")                                               \
    for (int mi = 0; mi < 4; mi++)                                  \
        af[mi] = *(const short8*)&Xs[B][aoff[mi]];                  \
    {   short8 bb[4];                                               \
        _Pragma("unroll")                                           \
        for (int ni = 0; ni < 4; ni++)                              \
            bb[ni] = *(const short8*)&Gs[B][boff[ni]];              \
        _Pragma("unroll")                                           \
        for (int mi = 0; mi < 4; mi++)                              \
        _Pragma("unroll")                                           \
        for (int ni = 0; ni < 4; ni++)                              \
            cg[mi][ni] = __builtin_amdgcn_mfma_f32_16x16x32_bf16(af[mi], bb[ni], cg[mi][ni], 0, 0, 0); \
    }                                                               \
    {   short8 bb[4];                                               \
        _Pragma("unroll")                                           \
        for (int ni = 0; ni < 4; ni++)                              \
            bb[ni] = *(const short8*)&Us[B][boff[ni]];              \
        _Pragma("unroll")                                           \
        for (int mi = 0; mi < 4; mi++)                              \
        _Pragma("unroll")                                           \
        for (int ni = 0; ni < 4; ni++)                              \
            cu[mi][ni] = __builtin_amdgcn_mfma_f32_16x16x32_bf16(af[mi], bb[ni], cu[mi][ni], 0, 0, 0); \
    } } while (0)

    // vmcnt trace: prologue 6 outstanding.  CVTW drains the 4 reg loads
    // (register dependency); WAITV(6) after issuing the next tile's 6 ops
    // drains the consumed tile's 2 X-DMA.  Tail: WAITV(0).
    XDMA(0, 0); LOADR(0);

    for (int tt = 0; tt < 32; tt += 2) {
        CVTW(0);
        XDMA(1, tt + 1); LOADR(tt + 1);
        WAITV(6); LGKM0; BAR();
        COMP1(0);
        BAR();
        CVTW(1);
        if (tt + 2 < 32) { XDMA(0, tt + 2); LOADR(tt + 2); WAITV(6); }
        else             { WAITV(0); }
        LGKM0; BAR();
        COMP1(1);
        BAR();
    }

#undef XDMA
#undef LOADR
#undef CVTW
#undef COMP1

    // epilogue: silu(g)*u -> bf16 hbuf.  C/D: col=lane&15, row=lq*4+reg
#pragma unroll
    for (int mi = 0; mi < 4; mi++)
#pragma unroll
        for (int r = 0; r < 4; r++) {
            int row = wm + mi * 16 + lq * 4 + r;
            int grow = row0 + row;
            if (grow < cnt) {
                short* hrow = hbuf + (size_t)(off_e + grow) * FFN + f0 + wn;
#pragma unroll
                for (int ni = 0; ni < 4; ni++) {
                    float g = cg[mi][ni][r], u = cu[mi][ni][r];
                    float h = g / (1.f + __expf(-g)) * u;
                    hrow[ni * 16 + l15] = f2bf(h);
                }
            }
        }
}

// ---------------- Stage B: BM=256 x BN=128, 8 waves, fp32 Wd direct ------------
// Demand 770 -> ~400 MB (Wd replicas 4 -> 2).  acc only 64 VGPR -> ~110 total
// -> 2 blocks/CU (16 waves).  Per wave per K-step: 2 H-DMA + 2 fp32 loads,
// 16 MFMA... (4x4 frags, one output) -- WAITV(4).
__global__ void __launch_bounds__(512, 2)
ffn2_v12(const short* __restrict__ hbuf, const float* __restrict__ Wd,
         const int* __restrict__ counts, const int* __restrict__ tok,
         const float* __restrict__ wts, float* __restrict__ out)
{
    int bid = blockIdx.x;                 // xb*128 + e*16 + y, xb slowest
    int xb  = bid >> 7;
    int yz  = bid & 127;
    int e   = yz >> 4;
    int y   = yz & 15;
    int cnt = counts[e];
    int row0 = xb * 256;
    if (row0 >= cnt) return;
    int off_e = 0;
#pragma unroll
    for (int i = 0; i < NEXP; i++) if (i < e) off_e += counts[i];
    int h0    = (y >> 1) * 128;
    int kbase = (y & 1) * (FFN / 2);

    __shared__ short Hs[2][256 * 32];
    __shared__ short Ds[2][128 * 32];
    __shared__ int   stok[256];
    __shared__ float swt[256];

    int tid = threadIdx.x;
    if (tid < 256) {
        int rc = min(row0 + tid, cnt - 1);
        stok[tid] = tok[e * NTOK + rc];
        swt[tid]  = wts[e * NTOK + rc];
    }
    __syncthreads();

    int lane = tid & 63, w = tid >> 6;
    int l15 = lane & 15, lq = lane >> 4;
    int wm = (w & 3) * 64, wn = (w >> 2) * 64;

    int prow   = lane >> 2;
    int gchunk = (lane & 3) ^ ((lane >> 3) & 3);

    const short* hsrc[2]; int hrb[2];
#pragma unroll
    for (int j = 0; j < 2; j++) {
        int rbase = w * 32 + j * 16;
        hsrc[j] = hbuf + (size_t)(off_e + min(row0 + rbase + prow, cnt - 1)) * FFN
                       + kbase + gchunk * 8;
        hrb[j] = rbase * 32;
    }
    const float* dsrc = Wd + (size_t)e * HIDDEN * FFN
                           + (size_t)(h0 + w * 16 + prow) * FFN + kbase + gchunk * 8;
    int wadr = (w * 16) * 32 + lane * 8;

    int aoff[4], boff[4];
#pragma unroll
    for (int mi = 0; mi < 4; mi++) {
        int r = wm + mi * 16 + l15;             // < 256
        aoff[mi] = r * 32 + (lq ^ ((r >> 1) & 3)) * 8;
    }
#pragma unroll
    for (int ni = 0; ni < 4; ni++) {
        int r = wn + ni * 16 + l15;             // < 128
        boff[ni] = r * 32 + (lq ^ ((r >> 1) & 3)) * 8;
    }

    f32x4 c[4][4];
#pragma unroll
    for (int i = 0; i < 4; i++)
#pragma unroll
        for (int j = 0; j < 4; j++) c[i][j] = (f32x4)0.f;

    float4 da_, db_;

#define HDMA(B, T) do { int _k = (T) * 32;                          \
    gl_lds16(hsrc[0] + _k, &Hs[B][hrb[0]]);                         \
    gl_lds16(hsrc[1] + _k, &Hs[B][hrb[1]]); } while (0)

#define LOADD(T) do { int _k = (T) * 32;                            \
    da_ = *(const float4*)(dsrc + _k);                              \
    db_ = *(const float4*)(dsrc + _k + 4); } while (0)

#define COMP2(B) do {                                               \
    short8 af[4], bd[4];                                            \
    _Pragma("unroll")                                               \
    for (int mi = 0; mi < 4; mi++)                                  \
        af[mi] = *(const short8*)&Hs[B][aoff[mi]];                  \
    _Pragma("unroll")                                               \
    for (int ni = 0; ni < 4; ni++)                                  \
        bd[ni] = *(const short8*)&Ds[B][boff[ni]];                  \
    _Pragma("unroll")                                               \
    for (int mi = 0; mi < 4; mi++)                                  \
    _Pragma("unroll")                                               \
    for (int ni = 0; ni < 4; ni++)                                  \
        c[mi][ni] = __builtin_amdgcn_mfma_f32_16x16x32_bf16(af[mi], bd[ni], c[mi][ni], 0, 0, 0); \
    } while (0)

    // 44 K-steps; 4 VMEM/wave/step; WAITV(4) drains consumed tile's H-DMA.
    HDMA(0, 0); LOADD(0);

    for (int tt = 0; tt < 44; tt += 2) {
        pk8(&Ds[0][wadr], da_, db_);          // reg-dep drains tile tt's Wd loads
        HDMA(1, tt + 1); LOADD(tt + 1);
        WAITV(4); LGKM0; BAR();
        COMP2(0);
        BAR();
        pk8(&Ds[1][wadr], da_, db_);
        if (tt + 2 < 44) { HDMA(0, tt + 2); LOADD(tt + 2); WAITV(4); }
        else             { WAITV(0); }
        LGKM0; BAR();
        COMP2(1);
        BAR();
    }

#undef HDMA
#undef LOADD
#undef COMP2

#pragma unroll
    for (int mi = 0; mi < 4; mi++)
#pragma unroll
        for (int r = 0; r < 4; r++) {
            int row = wm + mi * 16 + lq * 4 + r;
            int grow = row0 + row;
            if (grow < cnt) {
                int t = stok[row];
                float wgt = swt[row];
                float* orow = out + (size_t)t * HIDDEN + h0 + wn;
#pragma unroll
                for (int ni = 0; ni < 4; ni++)
                    atomicAdd(&orow[ni * 16 + l15], wgt * c[mi][ni][r]);
            }
        }
}

// ================= Fallback path (R2 kernels, used if ws too small) ============
#define LDW 40
__global__ void __launch_bounds__(256, 2)
ffn1_fb(const float* __restrict__ x, const float* __restrict__ Wg,
        const float* __restrict__ Wu, const int* __restrict__ counts,
        const int* __restrict__ tok, __hip_bfloat16* __restrict__ hbuf)
{
    int e = blockIdx.z;
    int cnt = counts[e];
    int row0 = blockIdx.x * 128;
    if (row0 >= cnt) return;
    int off_e = 0;
#pragma unroll
    for (int i = 0; i < NEXP; i++) if (i < e) off_e += counts[i];
    int f0 = blockIdx.y * 64;

    __shared__ short Xs[128][LDW];
    __shared__ short Gs[64][LDW];
    __shared__ short Us[64][LDW];
    __shared__ int   stok[128];

    int tid = threadIdx.x;
    if (tid < 128) stok[tid] = tok[e * NTOK + min(row0 + tid, cnt - 1)];
    __syncthreads();

    int lane = tid & 63, w = tid >> 6;
    int wm = (w & 1) * 64, wn = (w >> 1) * 32;
    int l15 = lane & 15, lq = lane >> 4;

    f32x4 cg[4][2], cu[4][2];
#pragma unroll
    for (int i = 0; i < 4; i++)
#pragma unroll
        for (int j = 0; j < 2; j++) { cg[i][j] = (f32x4)0.f; cu[i][j] = (f32x4)0.f; }

    const float* Wge = Wg + (size_t)e * FFN * HIDDEN;
    const float* Wue = Wu + (size_t)e * FFN * HIDDEN;

    int xr[4], xc[4]; const float* xp[4];
#pragma unroll
    for (int i = 0; i < 4; i++) {
        int idx = tid + 256 * i;
        xr[i] = idx >> 3; xc[i] = (idx & 7) * 4;
        xp[i] = x + (size_t)stok[xr[i]] * HIDDEN + xc[i];
    }
    int wr[2], wc[2]; const float* gp[2]; const float* up[2];
#pragma unroll
    for (int i = 0; i < 2; i++) {
        int idx = tid + 256 * i;
        wr[i] = idx >> 3; wc[i] = (idx & 7) * 4;
        gp[i] = Wge + (size_t)(f0 + wr[i]) * HIDDEN + wc[i];
        up[i] = Wue + (size_t)(f0 + wr[i]) * HIDDEN + wc[i];
    }

    float4 xa[4], ga[2], ua[2];
#pragma unroll
    for (int i = 0; i < 4; i++) xa[i] = *(const float4*)(xp[i]);
#pragma unroll
    for (int i = 0; i < 2; i++) { ga[i] = *(const float4*)(gp[i]); ua[i] = *(const float4*)(up[i]); }

    for (int k0 = 0; k0 < HIDDEN; k0 += 32) {
        __syncthreads();
#pragma unroll
        for (int i = 0; i < 4; i++) {
            short* d = &Xs[xr[i]][xc[i]];
            d[0] = f2bf(xa[i].x); d[1] = f2bf(xa[i].y);
            d[2] = f2bf(xa[i].z); d[3] = f2bf(xa[i].w);
        }
#pragma unroll
        for (int i = 0; i < 2; i++) {
            short* d = &Gs[wr[i]][wc[i]];
            d[0] = f2bf(ga[i].x); d[1] = f2bf(ga[i].y);
            d[2] = f2bf(ga[i].z); d[3] = f2bf(ga[i].w);
            short* d2 = &Us[wr[i]][wc[i]];
            d2[0] = f2bf(ua[i].x); d2[1] = f2bf(ua[i].y);
            d2[2] = f2bf(ua[i].z); d2[3] = f2bf(ua[i].w);
        }
        __syncthreads();
        if (k0 + 32 < HIDDEN) {
            int kn = k0 + 32;
#pragma unroll
            for (int i = 0; i < 4; i++) xa[i] = *(const float4*)(xp[i] + kn);
#pragma unroll
            for (int i = 0; i < 2; i++) { ga[i] = *(const float4*)(gp[i] + kn); ua[i] = *(const float4*)(up[i] + kn); }
        }
        short8 af[4], bg[2], bu[2];
#pragma unroll
        for (int mi = 0; mi < 4; mi++) af[mi] = *(const short8*)&Xs[wm + mi * 16 + l15][lq * 8];
#pragma unroll
        for (int ni = 0; ni < 2; ni++) {
            bg[ni] = *(const short8*)&Gs[wn + ni * 16 + l15][lq * 8];
            bu[ni] = *(const short8*)&Us[wn + ni * 16 + l15][lq * 8];
        }
#pragma unroll
        for (int mi = 0; mi < 4; mi++)
#pragma unroll
            for (int ni = 0; ni < 2; ni++) {
                cg[mi][ni] = __builtin_amdgcn_mfma_f32_16x16x32_bf16(af[mi], bg[ni], cg[mi][ni], 0, 0, 0);
                cu[mi][ni] = __builtin_amdgcn_mfma_f32_16x16x32_bf16(af[mi], bu[ni], cu[mi][ni], 0, 0, 0);
            }
    }

#pragma unroll
    for (int mi = 0; mi < 4; mi++)
#pragma unroll
        for (int r = 0; r < 4; r++) {
            int row = wm + mi * 16 + lq * 4 + r;
            int grow = row0 + row;
            if (grow < cnt) {
                __hip_bfloat16* hrow = hbuf + (size_t)(off_e + grow) * FFN + f0 + wn;
#pragma unroll
                for (int ni = 0; ni < 2; ni++) {
                    float g = cg[mi][ni][r], u = cu[mi][ni][r];
                    float h = g / (1.f + __expf(-g)) * u;
                    hrow[ni * 16 + l15] = __float2bfloat16(h);
                }
            }
        }
}

__global__ void __launch_bounds__(256, 2)
ffn2_fb(const __hip_bfloat16* __restrict__ hbuf, const float* __restrict__ Wd,
        const int* __restrict__ counts, const int* __restrict__ tok,
        const float* __restrict__ wts, float* __restrict__ out)
{
    int e = blockIdx.z;
    int cnt = counts[e];
    int row0 = blockIdx.x * 128;
    if (row0 >= cnt) return;
    int off_e = 0;
#pragma unroll
    for (int i = 0; i < NEXP; i++) if (i < e) off_e += counts[i];
    int h0 = blockIdx.y * 64;

    __shared__ short Hs[128][LDW];
    __shared__ short Ds[64][LDW];
    __shared__ int   stok[128];
    __shared__ float swt[128];

    int tid = threadIdx.x;
    if (tid < 128) {
        int rc = min(row0 + tid, cnt - 1);
        stok[tid] = tok[e * NTOK + rc];
        swt[tid]  = wts[e * NTOK + rc];
    }
    __syncthreads();

    int lane = tid & 63, w = tid >> 6;
    int wm = (w & 1) * 64, wn = (w >> 1) * 32;
    int l15 = lane & 15, lq = lane >> 4;

    f32x4 c[4][2];
#pragma unroll
    for (int i = 0; i < 4; i++)
#pragma unroll
        for (int j = 0; j < 2; j++) c[i][j] = (f32x4)0.f;

    const float* Wde = Wd + (size_t)e * HIDDEN * FFN;

    int hr[2], hc[2]; const short* hp[2];
#pragma unroll
    for (int i = 0; i < 2; i++) {
        int idx = tid + 256 * i;
        hr[i] = idx >> 2; hc[i] = (idx & 3) * 8;
        int ar = min(row0 + hr[i], cnt - 1);
        hp[i] = (const short*)(hbuf + (size_t)(off_e + ar) * FFN + hc[i]);
    }
    int dr[2], dc[2]; const float* dp[2];
#pragma unroll
    for (int i = 0; i < 2; i++) {
        int idx = tid + 256 * i;
        dr[i] = idx >> 3; dc[i] = (idx & 7) * 4;
        dp[i] = Wde + (size_t)(h0 + dr[i]) * FFN + dc[i];
    }

    short8 ha[2]; float4 da[2];
#pragma unroll
    for (int i = 0; i < 2; i++) { ha[i] = *(const short8*)(hp[i]); da[i] = *(const float4*)(dp[i]); }

    for (int k0 = 0; k0 < FFN; k0 += 32) {
        __syncthreads();
#pragma unroll
        for (int i = 0; i < 2; i++) {
            *(short8*)&Hs[hr[i]][hc[i]] = ha[i];
            short* d = &Ds[dr[i]][dc[i]];
            d[0] = f2bf(da[i].x); d[1] = f2bf(da[i].y);
            d[2] = f2bf(da[i].z); d[3] = f2bf(da[i].w);
        }
        __syncthreads();
        if (k0 + 32 < FFN) {
            int kn = k0 + 32;
#pragma unroll
            for (int i = 0; i < 2; i++) { ha[i] = *(const short8*)(hp[i] + kn); da[i] = *(const float4*)(dp[i] + kn); }
        }
        short8 af[4], bf_[2];
#pragma unroll
        for (int mi = 0; mi < 4; mi++) af[mi] = *(const short8*)&Hs[wm + mi * 16 + l15][lq * 8];
#pragma unroll
        for (int ni = 0; ni < 2; ni++) bf_[ni] = *(const short8*)&Ds[wn + ni * 16 + l15][lq * 8];
#pragma unroll
        for (int mi = 0; mi < 4; mi++)
#pragma unroll
            for (int ni = 0; ni < 2; ni++)
                c[mi][ni] = __builtin_amdgcn_mfma_f32_16x16x32_bf16(af[mi], bf_[ni], c[mi][ni], 0, 0, 0);
    }

#pragma unroll
    for (int mi = 0; mi < 4; mi++)
#pragma unroll
        for (int r = 0; r < 4; r++) {
            int row = wm + mi * 16 + lq * 4 + r;
            int grow = row0 + row;
            if (grow < cnt) {
                int t = stok[row];
                float wgt = swt[row];
                float* orow = out + (size_t)t * HIDDEN + h0 + wn;
#pragma unroll
                for (int ni = 0; ni < 2; ni++)
                    atomicAdd(&orow[ni * 16 + l15], wgt * c[mi][ni][r]);
            }
        }
}

extern "C" void kernel_launch(void* const* d_in, const int* in_sizes, int n_in,
                              void* d_out, int out_size, void* d_ws, size_t ws_size,
                              hipStream_t stream) {
    const float* x     = (const float*)d_in[0];
    const float* Wgate = (const float*)d_in[1];
    const float* Wg    = (const float*)d_in[2];
    const float* Wu    = (const float*)d_in[3];
    const float* Wd    = (const float*)d_in[4];
    float* out = (float*)d_out;

    char* ws = (char*)d_ws;
    int*   counts = (int*)ws;
    int*   tok    = (int*)(ws + 256);
    float* wts    = (float*)(ws + 256 + NEXP * NTOK * 4);

    hipMemsetAsync(counts, 0, 256, stream);

    const size_t base = 256 + 2 * (size_t)NEXP * NTOK * 4;   // 131328
    const size_t NEED = base
        + 2ull * NTOK * HIDDEN                // xbf
        + 2ull * 2ull * NTOK * FFN;           // hbuf (4096 x 2816)

    if (ws_size >= NEED) {
        short* xbf  = (short*)(ws + base);
        short* hbuf = xbf + (size_t)NTOK * HIDDEN;

        // launch 1: router + x->bf16 + out zero-fill (round-6 proven)
        fused_rxz<<<1536, 256, 0, stream>>>(x, Wgate, counts, tok, wts, xbf, out);

        // launch 2: ffn1, BM=256 demand-halved (fp32 weights direct)
        ffn1_v12<<<FFN1_BLOCKS, 512, 0, stream>>>(xbf, Wg, Wu, counts, tok, hbuf);

        // launch 3: ffn2, BM=256 demand-halved (fp32 Wd direct)
        ffn2_v12<<<1024, 512, 0, stream>>>(hbuf, Wd, counts, tok, wts, out);
    } else {
        hipMemsetAsync(out, 0, (size_t)out_size * sizeof(float), stream);
        router_kernel<<<NTOK, 64, 0, stream>>>(x, Wgate, counts, tok, wts);
        __hip_bfloat16* hbuf = (__hip_bfloat16*)(ws + base);
        dim3 g1(NTOK / 128, FFN / 64, NEXP);
        ffn1_fb<<<g1, 256, 0, stream>>>(x, Wg, Wu, counts, tok, hbuf);
        dim3 g2(NTOK / 128, HIDDEN / 64, NEXP);
        ffn2_fb<<<g2, 256, 0, stream>>>(hbuf, Wd, counts, tok, wts, out);
    }
}